// Round 14
// baseline (700.407 us; speedup 1.0000x reference)
//
#include <hip/hip_runtime.h>

// VQ-VAE vector-quantize, fused: distances + argmin + gather + loss.
// x: [65536, 256] fp32, dict: [256, 1024] fp32.
// out: q_ste [65536*256] fp32, then loss scalar at out[65536*256].
//
// NUMERICS (bit-exact vs np reference, verified absmax 0.0 R2-R18 — DO NOT CHANGE):
//  - row norm ||f||^2: np pairwise tree (two INDEPENDENT 128-halves, each an
//    8-accumulator r8[e&7] chain, unfused squares, fixed combine tree,
//    result = half0_tree + half1_tree)
//  - enorm ||e||^2: sequential d ascending, unfused square then plain add
//  - dot chain per (row,code): fma, d strictly ascending per ct (s-loop
//    ct-major, dd inner), acc zeroed per ct — order identical to R12.
//  - dist = fl( fl(A + B) - 2*s ); argmin strict < with codes ascending
//    (first index on ties); cross-lane combine uses the associative
//    first-index rule (v<bv)||(v==bv&&i<bi) — order-independent.
//  - STE out = fl(x + fl(q - x)); loss on pure q, (1+BETA)/(N*D) scale
//  - xpose is a bit-exact copy.
//
// PERF (R18 -> R19): 14 variants pin the residual on LDS instruction issue:
// 768 ds_read_b128/CU-step (~9.2k cyc on the per-CU LDS pipe) because BOTH
// operands live in LDS (6 b128/lane/dd is minimal for that). R19 moves the
// f-operand to the SCALAR pipe: wave owns 8 consecutive rows -> f from
// xT[d][row] via uniform (readfirstlane-based) s_load; lane owns 4 codes ->
// ONE ds_read_b128/dd (1KB contiguous, conflict-free). acc = v4[8] = 32 VGPR
// (no spill, no R17-AGPR trap). x-staging + fx ds_writes + their drain gone.
// xT (64MB) lives in workspace; host falls back to the verified R12 kernel
// if ws_size is too small.

#define NROWS 65536
#define DDIM  256
#define KC    1024
#define BC    256            // codes per ct tile
#define DC    16             // d-chunk per step
#define NSTEP 64             // 4 ct x 16 dc
#define FXW   128            // (R12 fallback) x-tile pitch

typedef float v4 __attribute__((ext_vector_type(4)));

#define GLOAD_LDS16(gp, lp) __builtin_amdgcn_global_load_lds( \
    (const __attribute__((address_space(1))) void*)(gp),      \
    (__attribute__((address_space(3))) void*)(lp), 16, 0, 0)

// dict tile [16 d][256 codes] via DMA — 512-thread version (2 instrs).
#define STAGE_DICT512(pbuf, ct_, dc_) do {                                      \
    _Pragma("unroll")                                                           \
    for (int i_ = 0; i_ < 2; ++i_) {                                            \
        int flat_ = i_ * 512 + tid;                                             \
        int dd_ = flat_ >> 6;            /* wave-uniform */                     \
        int l4_ = (flat_ & 63) * 4;                                             \
        GLOAD_LDS16(&dict[(size_t)((dc_) * DC + dd_) * KC + (ct_) * BC + l4_],  \
                    (pbuf) + dd_ * BC + l4_);                                   \
    }                                                                           \
} while (0)

// dict tile — 256-thread version (4 instrs), for the R12 fallback kernel.
#define STAGE_DICT256(pbuf, ct_, dc_) do {                                      \
    _Pragma("unroll")                                                           \
    for (int i_ = 0; i_ < 4; ++i_) {                                            \
        int flat_ = i_ * 256 + tid;                                             \
        int dd_ = flat_ >> 6;                                                   \
        int l4_ = (flat_ & 63) * 4;                                             \
        GLOAD_LDS16(&dict[(size_t)((dc_) * DC + dd_) * KC + (ct_) * BC + l4_],  \
                    (pbuf) + dd_ * BC + l4_);                                   \
    }                                                                           \
} while (0)

// (R12 fallback) x chunk [128 rows][16 d] -> LDS transposed [d][row].
#define STAGE_FX256(dstbuf, dc_) do {                                           \
    const int r0_ = tid >> 2, c0_ = tid & 3;                                    \
    const float4 v0_ = *(const float4*)&x[(size_t)(rowbase + r0_) * DDIM + (dc_) * DC + c0_ * 4];      \
    const float4 v1_ = *(const float4*)&x[(size_t)(rowbase + 64 + r0_) * DDIM + (dc_) * DC + c0_ * 4]; \
    float* b0_ = (dstbuf) + (c0_ * 4) * FXW + r0_;                              \
    b0_[0 * FXW] = v0_.x; b0_[1 * FXW] = v0_.y;                                 \
    b0_[2 * FXW] = v0_.z; b0_[3 * FXW] = v0_.w;                                 \
    float* b1_ = b0_ + 64;                                                      \
    b1_[0 * FXW] = v1_.x; b1_[1 * FXW] = v1_.y;                                 \
    b1_[2 * FXW] = v1_.z; b1_[3 * FXW] = v1_.w;                                 \
} while (0)

// Pre-kernel: codebook column norms (np order) + transposed codebook + loss=0.
__global__ __launch_bounds__(64) void vq_prep(const float* __restrict__ dict,
                                              float* __restrict__ enorm,
                                              float* __restrict__ dictT,
                                              float* __restrict__ loss) {
#pragma clang fp contract(off)
    int k = blockIdx.x * 64 + threadIdx.x;
    if (k == 0) *loss = 0.f;   // runs before vq_main (stream order)
    float s = 0.f;
    #pragma unroll 8
    for (int d = 0; d < DDIM; ++d) {
        float v = dict[(size_t)d * KC + k];
        float sq = v * v;          // rounded square (np temp array)
        s = s + sq;                // plain add, NOT fma
        dictT[(size_t)k * DDIM + d] = v;
    }
    enorm[k] = s;
}

// Transpose x -> xT[256][65536] in 64x64 LDS tiles (bit-exact copy).
__global__ __launch_bounds__(256) void vq_xpose(const float* __restrict__ x,
                                                float* __restrict__ xT) {
    __shared__ float tile[64][65];
    const int tid = threadIdx.x;
    const int tr = blockIdx.x & 1023;    // row tile (64 rows)
    const int tc = blockIdx.x >> 10;     // d tile (0..3, 64 d each)
    const int rb = tr * 64, db = tc * 64;
    #pragma unroll
    for (int pass = 0; pass < 4; ++pass) {
        int rl = pass * 16 + (tid >> 4);
        int dl = (tid & 15) * 4;
        float4 v = *(const float4*)&x[(size_t)(rb + rl) * DDIM + db + dl];
        tile[rl][dl + 0] = v.x; tile[rl][dl + 1] = v.y;
        tile[rl][dl + 2] = v.z; tile[rl][dl + 3] = v.w;
    }
    __syncthreads();
    #pragma unroll
    for (int pass = 0; pass < 4; ++pass) {
        int dl = pass * 16 + (tid >> 4);
        int rl = (tid & 15) * 4;
        float4 w;
        w.x = tile[rl + 0][dl]; w.y = tile[rl + 1][dl];
        w.z = tile[rl + 2][dl]; w.w = tile[rl + 3][dl];
        *(float4*)&xT[(size_t)(db + dl) * NROWS + rb + rl] = w;
    }
}

// ---- New main: wave = 8 consecutive rows (f uniform via s_load from xT),
// lane = 4 codes (one conflict-free ds_read_b128 per dd). 512 thr, 64 rows.
__global__ __launch_bounds__(512) void vq_main_t(const float* __restrict__ x,
                                                 const float* __restrict__ xT,
                                                 const float* __restrict__ dict,
                                                 const float* __restrict__ enorm,
                                                 const float* __restrict__ dictT,
                                                 float* __restrict__ out,
                                                 float* __restrict__ loss) {
    __shared__ float dTs[2][DC * BC];    // 16 KB x2
    __shared__ float rnormS[64];
    __shared__ int   idx_s[64];

    const int tid = threadIdx.x;
    const int l   = tid & 63;                              // lane = code group
    const int wu  = __builtin_amdgcn_readfirstlane(tid >> 6);  // wave = row octet
    const int rowbase = blockIdx.x * 64;

    STAGE_DICT512(&dTs[0][0], 0, 0);     // tile (0,0) DMA overlaps rnorm

    // Block-local row norms: verified np two-half chain, 2 threads/row (64 rows).
    if (tid < 128) {
#pragma clang fp contract(off)
        const int row  = tid >> 1;
        const int half = tid & 1;
        const float* xr = x + (size_t)(rowbase + row) * DDIM + half * 128;
        float r8[8] = {0.f, 0.f, 0.f, 0.f, 0.f, 0.f, 0.f, 0.f};
        #pragma unroll 8
        for (int c = 0; c < 32; ++c) {   // local e = 4c..4c+3 ; e&7 == (c&1)*4+k
            float4 v = *(const float4*)&xr[c * 4];
            int b = (c & 1) * 4;
            float s0 = v.x * v.x; r8[b + 0] = r8[b + 0] + s0;
            float s1 = v.y * v.y; r8[b + 1] = r8[b + 1] + s1;
            float s2 = v.z * v.z; r8[b + 2] = r8[b + 2] + s2;
            float s3 = v.w * v.w; r8[b + 3] = r8[b + 3] + s3;
        }
        float h = ((r8[0] + r8[1]) + (r8[2] + r8[3]))
                + ((r8[4] + r8[5]) + (r8[6] + r8[7]));
        float ho = __shfl_down(h, 1, 64);
        if (half == 0) rnormS[row] = h + ho;  // fl(half0 + half1)
    }
    __syncthreads();                     // dict(0,0) staged + rnormS live

    float Arow[8];
    #pragma unroll
    for (int r = 0; r < 8; ++r) Arow[r] = rnormS[wu * 8 + r];

    float minv[8];
    int   mini[8];
    #pragma unroll
    for (int r = 0; r < 8; ++r) { minv[r] = 3.4e38f; mini[r] = 0; }

    v4 acc[8];                           // 8 rows x 4 codes = 32 VGPR
    #pragma unroll 2                     // compile-time buffer parity
    for (int s = 0; s < NSTEP; ++s) {
        const int p = s & 1;
        if (s < NSTEP - 1) {
            const int ns = s + 1;
            STAGE_DICT512(&dTs[1 - p][0], ns >> 4, ns & 15);   // async, 0 regs
        }
        if ((s & 15) == 0) {
            #pragma unroll
            for (int r = 0; r < 8; ++r) acc[r] = (v4){0.f, 0.f, 0.f, 0.f};
        }
        const int dc = s & 15;
        // Uniform f base: xT[d][rowbase + wu*8 .. +7] (8 consecutive floats).
        const float* __restrict__ xw =
            xT + (size_t)(dc * DC) * NROWS + rowbase + wu * 8;
        #pragma unroll 4
        for (int dd = 0; dd < DC; ++dd) {
            const float* __restrict__ fp = xw + (size_t)dd * NROWS;  // uniform
            const v4 e4 = *(const v4*)&dTs[p][dd * BC + l * 4];      // 1 b128
            #pragma unroll
            for (int r = 0; r < 8; ++r) {
                const float fv = fp[r];          // uniform -> s_load / SGPR
                acc[r] = __builtin_elementwise_fma((v4){fv, fv, fv, fv},
                                                   e4, acc[r]);
            }
        }
        if ((s & 15) == 15) {
            // dist = fl( fl(A + B) - 2*s ); codes ascend (ct, j) per lane ->
            // strict < keeps FIRST min index.
            const int cbase = (s >> 4) * BC;
            const v4 en = *(const v4*)&enorm[cbase + l * 4];
            #pragma unroll
            for (int r = 0; r < 8; ++r)
                #pragma unroll
                for (int j = 0; j < 4; ++j) {
                    int code = cbase + l * 4 + j;
                    float t1 = Arow[r] + en[j];
                    float dist = t1 - 2.0f * acc[r][j];
                    if (dist < minv[r]) { minv[r] = dist; mini[r] = code; }
                }
        }
        __syncthreads();
    }

    // Full 64-lane butterfly argmin per row (associative first-index rule).
    #pragma unroll
    for (int m = 1; m < 64; m <<= 1)
        #pragma unroll
        for (int r = 0; r < 8; ++r) {
            float ov = __shfl_xor(minv[r], m, 64);
            int   oi = __shfl_xor(mini[r], m, 64);
            if (ov < minv[r] || (ov == minv[r] && oi < mini[r])) {
                minv[r] = ov; mini[r] = oi;
            }
        }
    if (l == 0) {
        #pragma unroll
        for (int r = 0; r < 8; ++r) idx_s[wu * 8 + r] = mini[r];
    }
    __syncthreads();

    // Epilogue: 512 thr = 256 cols x 2 row-halves over 64 rows. Per-element
    // chains unchanged (lsum regrouping harness-tolerated per R8/R14).
    float lsum = 0.f;
    {
#pragma clang fp contract(off)
        const int ecol = tid & 255;
        const int erh  = tid >> 8;
        #pragma unroll 2
        for (int i = 0; i < 32; ++i) {
            int row = erh * 32 + i;
            int k = idx_s[row];
            float qv = dictT[(size_t)k * DDIM + ecol];
            float xv = x[(size_t)(rowbase + row) * DDIM + ecol];
            float diff = qv - xv;                                 // fl(q - x)
            __builtin_nontemporal_store(xv + diff,
                &out[(size_t)(rowbase + row) * DDIM + ecol]);     // fl(x+fl(q-x))
            float d = xv - qv;
            float dsq = d * d;
            lsum = lsum + dsq;
        }
    }
    #pragma unroll
    for (int off = 32; off > 0; off >>= 1)
        lsum += __shfl_down(lsum, off, 64);
    if ((tid & 63) == 0)
        atomicAdd(loss, lsum * (1.25f / 16777216.0f));  // (1+BETA)/(N*D)
}

// ---- R12 fallback main (verified 462us, absmax 0.0) — used if ws too small.
__global__ __launch_bounds__(256, 2) void vq_main_r12(const float* __restrict__ x,
                                                      const float* __restrict__ dict,
                                                      const float* __restrict__ enorm,
                                                      const float* __restrict__ dictT,
                                                      float* __restrict__ out,
                                                      float* __restrict__ loss) {
    __shared__ float fXb[2][DC * FXW];
    __shared__ float dTs[2][DC * BC];
    __shared__ float rnormS[128];

    const int tid = threadIdx.x;
    const int tx  = tid & 15;
    const int ty  = tid >> 4;
    const int rowbase = blockIdx.x * 128;

    STAGE_DICT256(&dTs[0][0], 0, 0);
    {
#pragma clang fp contract(off)
        const int row  = tid >> 1;
        const int half = tid & 1;
        const float* xr = x + (size_t)(rowbase + row) * DDIM + half * 128;
        float r8[8] = {0.f, 0.f, 0.f, 0.f, 0.f, 0.f, 0.f, 0.f};
        #pragma unroll 8
        for (int c = 0; c < 32; ++c) {
            float4 v = *(const float4*)&xr[c * 4];
            int b = (c & 1) * 4;
            float s0 = v.x * v.x; r8[b + 0] = r8[b + 0] + s0;
            float s1 = v.y * v.y; r8[b + 1] = r8[b + 1] + s1;
            float s2 = v.z * v.z; r8[b + 2] = r8[b + 2] + s2;
            float s3 = v.w * v.w; r8[b + 3] = r8[b + 3] + s3;
        }
        float h = ((r8[0] + r8[1]) + (r8[2] + r8[3]))
                + ((r8[4] + r8[5]) + (r8[6] + r8[7]));
        float ho = __shfl_down(h, 1, 64);
        if (half == 0) rnormS[row] = h + ho;
    }
    STAGE_FX256(&fXb[0][0], 0);
    __syncthreads();

    float Arow[8];
    #pragma unroll
    for (int r = 0; r < 8; ++r) Arow[r] = rnormS[ty * 8 + r];
    float minv[8]; int mini[8];
    #pragma unroll
    for (int r = 0; r < 8; ++r) { minv[r] = 3.4e38f; mini[r] = 0; }

    float acc[8][16];
    #pragma unroll 2
    for (int s = 0; s < NSTEP; ++s) {
        const int p = s & 1;
        if (s < NSTEP - 1) {
            const int ns = s + 1;
            STAGE_DICT256(&dTs[1 - p][0], ns >> 4, ns & 15);
            STAGE_FX256(&fXb[1 - p][0], ns & 15);
        }
        if ((s & 15) == 0) {
            #pragma unroll
            for (int r = 0; r < 8; ++r)
                #pragma unroll
                for (int j = 0; j < 16; ++j) acc[r][j] = 0.f;
        }
        #pragma unroll 4
        for (int dd = 0; dd < DC; ++dd) {
            const float4 f0 = *(const float4*)&fXb[p][dd * FXW + ty * 8];
            const float4 f1 = *(const float4*)&fXb[p][dd * FXW + ty * 8 + 4];
            const float4 e0 = *(const float4*)&dTs[p][dd * BC + tx * 4];
            const float4 e1 = *(const float4*)&dTs[p][dd * BC + 64 + tx * 4];
            const float4 e2 = *(const float4*)&dTs[p][dd * BC + 128 + tx * 4];
            const float4 e3 = *(const float4*)&dTs[p][dd * BC + 192 + tx * 4];
            const float fr[8]  = {f0.x, f0.y, f0.z, f0.w, f1.x, f1.y, f1.z, f1.w};
            const float ec[16] = {e0.x, e0.y, e0.z, e0.w, e1.x, e1.y, e1.z, e1.w,
                                  e2.x, e2.y, e2.z, e2.w, e3.x, e3.y, e3.z, e3.w};
            #pragma unroll
            for (int r = 0; r < 8; ++r)
                #pragma unroll
                for (int j = 0; j < 16; ++j)
                    acc[r][j] = fmaf(fr[r], ec[j], acc[r][j]);
        }
        if ((s & 15) == 15) {
            const int cbase = (s >> 4) * BC;
            float en[16];
            #pragma unroll
            for (int j = 0; j < 16; ++j)
                en[j] = enorm[cbase + (j >> 2) * 64 + tx * 4 + (j & 3)];
            #pragma unroll
            for (int r = 0; r < 8; ++r)
                #pragma unroll
                for (int j = 0; j < 16; ++j) {
                    int code = cbase + (j >> 2) * 64 + tx * 4 + (j & 3);
                    float t1 = Arow[r] + en[j];
                    float dist = t1 - 2.0f * acc[r][j];
                    if (dist < minv[r]) { minv[r] = dist; mini[r] = code; }
                }
        }
        __syncthreads();
    }

    #pragma unroll
    for (int m = 1; m < 16; m <<= 1)
        #pragma unroll
        for (int r = 0; r < 8; ++r) {
            float ov = __shfl_xor(minv[r], m, 64);
            int   oi = __shfl_xor(mini[r], m, 64);
            if (ov < minv[r] || (ov == minv[r] && oi < mini[r])) {
                minv[r] = ov; mini[r] = oi;
            }
        }
    int* idx_s = (int*)&dTs[0][0];
    if (tx == 0) {
        #pragma unroll
        for (int r = 0; r < 8; ++r) idx_s[ty * 8 + r] = mini[r];
    }
    __syncthreads();

    float lsum = 0.f;
    {
#pragma clang fp contract(off)
        #pragma unroll 2
        for (int i = 0; i < 128; ++i) {
            int k = idx_s[i];
            float qv = dictT[(size_t)k * DDIM + tid];
            float xv = x[(size_t)(rowbase + i) * DDIM + tid];
            float diff = qv - xv;
            __builtin_nontemporal_store(xv + diff,
                &out[(size_t)(rowbase + i) * DDIM + tid]);
            float d = xv - qv;
            float dsq = d * d;
            lsum = lsum + dsq;
        }
    }
    #pragma unroll
    for (int off = 32; off > 0; off >>= 1)
        lsum += __shfl_down(lsum, off, 64);
    if ((tid & 63) == 0)
        atomicAdd(loss, lsum * (1.25f / 16777216.0f));
}

extern "C" void kernel_launch(void* const* d_in, const int* in_sizes, int n_in,
                              void* d_out, int out_size, void* d_ws, size_t ws_size,
                              hipStream_t stream) {
    (void)in_sizes; (void)n_in; (void)out_size;
    const float* x    = (const float*)d_in[0];
    const float* dict = (const float*)d_in[1];
    float* out   = (float*)d_out;
    float* enorm = (float*)d_ws;                 // 1024 floats
    float* dictT = enorm + KC;                   // 1 MB
    float* xT    = dictT + (size_t)KC * DDIM;    // 64 MB (if it fits)
    float* loss  = out + (size_t)NROWS * DDIM;   // scalar slot after q

    const size_t need = (size_t)KC * 4 + (size_t)KC * DDIM * 4
                      + (size_t)DDIM * NROWS * 4;

    vq_prep<<<KC / 64, 64, 0, stream>>>(dict, enorm, dictT, loss);
    if (ws_size >= need) {
        vq_xpose<<<4096, 256, 0, stream>>>(x, xT);
        vq_main_t<<<NROWS / 64, 512, 0, stream>>>(x, xT, dict, enorm, dictT,
                                                  out, loss);
    } else {
        vq_main_r12<<<NROWS / 128, 256, 0, stream>>>(x, dict, enorm, dictT,
                                                     out, loss);
    }
}